// Round 4
// baseline (238.214 us; speedup 1.0000x reference)
//
#include <hip/hip_runtime.h>

#define BATCH 32
#define SEQ 512
#define CH 384
#define CH4 96            // float4 per channel row
#define MAXL 4096
#define K2T 384           // 6 waves: thread = (lr 0..3, c4 0..95), computed once
#define K2G 32            // rows per expand block

typedef float v4f __attribute__((ext_vector_type(4)));

// Kernel 1 (verified exact in R1): per-batch cumsum -> interval scatter of the
// t->frame-index table into ws (normal stores, re-read by K2), mask to d_out
// tail (NT stores, never re-read). 32 blocks x 512 threads; ~5 us.
__global__ __launch_bounds__(SEQ) void lr_scan_kernel(
    const int* __restrict__ durations,
    const int* __restrict__ max_len_p,
    int* __restrict__ ws_idx,
    float* __restrict__ out_mask)
{
    __shared__ int s_cum[SEQ];
    __shared__ int s_idx[MAXL];

    const int tid = threadIdx.x;
    const int b = blockIdx.x;
    const int maxlen = max_len_p[0];

    s_cum[tid] = durations[b * SEQ + tid];
    __syncthreads();
    #pragma unroll
    for (int off = 1; off < SEQ; off <<= 1) {
        int v = (tid >= off) ? s_cum[tid - off] : 0;
        __syncthreads();
        s_cum[tid] += v;
        __syncthreads();
    }

    for (int t = tid; t < MAXL; t += SEQ) s_idx[t] = -1;  // -1 == masked
    __syncthreads();

    // frame tid covers [ends[tid-1], ends[tid]) after clip; intervals disjoint,
    // tile [0,total); matches searchsorted(ends, t, 'right') incl. dup-ends.
    int e  = min(s_cum[tid], maxlen);
    int st = (tid == 0) ? 0 : min(s_cum[tid - 1], maxlen);
    for (int t = st; t < e; ++t) s_idx[t] = tid;
    __syncthreads();

    for (int t = tid; t < MAXL; t += SEQ) {
        int v = s_idx[t];
        ws_idx[b * MAXL + t] = v;
        __builtin_nontemporal_store((v < 0) ? 1.0f : 0.0f,
                                    &out_mask[b * MAXL + t]);
    }
}

// Kernel 2: fill-like streaming expand. No LDS, no barriers. Each thread owns
// a fixed (row-slot, c4) and walks 8 rows at constant address stride; 8
// independent idx loads -> 8 x loads -> 8 NT stores per thread.
__global__ __launch_bounds__(K2T) void lr_expand_kernel(
    const v4f* __restrict__ x,
    const int* __restrict__ ws_idx,
    v4f* __restrict__ out)
{
    const int tid = threadIdx.x;
    const int lr  = tid / CH4;          // 0..3 (computed once)
    const int c4  = tid - lr * CH4;     // 0..95
    const int r0  = blockIdx.x * K2G + lr;

    #pragma unroll
    for (int k = 0; k < K2G / 4; ++k) {
        int r   = r0 + 4 * k;           // global row = b*4096 + t
        int idx = ws_idx[r];            // L1-hot broadcast across the 96 lanes
        int b   = r >> 12;
        v4f v = (v4f){0.f, 0.f, 0.f, 0.f};
        if (idx >= 0) v = x[(b * SEQ + idx) * CH4 + c4];   // cached read
        __builtin_nontemporal_store(v, &out[(size_t)r * CH4 + c4]);
    }
}

extern "C" void kernel_launch(void* const* d_in, const int* in_sizes, int n_in,
                              void* d_out, int out_size, void* d_ws, size_t ws_size,
                              hipStream_t stream) {
    const v4f* x = (const v4f*)d_in[0];
    const int* durations = (const int*)d_in[1];
    const int* max_len_p = (const int*)d_in[2];
    float* out = (float*)d_out;
    float* out_mask = out + (size_t)BATCH * MAXL * CH;
    int* ws_idx = (int*)d_ws;   // BATCH*MAXL ints = 512 KB

    lr_scan_kernel<<<BATCH, SEQ, 0, stream>>>(durations, max_len_p, ws_idx, out_mask);
    lr_expand_kernel<<<(BATCH * MAXL) / K2G, K2T, 0, stream>>>(
        x, ws_idx, (v4f*)out);
}

// Round 5
// 218.835 us; speedup vs baseline: 1.0886x; 1.0886x over previous
//
#include <hip/hip_runtime.h>

#define BATCH 32
#define SEQ 512
#define CH 384
#define CH4 96            // float4 per channel row
#define MAXL 4096
#define ZBLK 64           // zero-fill blocks per batch

typedef float v4f __attribute__((ext_vector_type(4)));

// Kernel 1: per-batch inclusive cumsum of durations -> clipped `ends` (ws),
// plus mel_mask (t >= total) to d_out tail. 32 blocks x 512 threads, ~6 us.
__global__ __launch_bounds__(SEQ) void lr_scan_kernel(
    const int* __restrict__ durations,
    const int* __restrict__ max_len_p,
    int* __restrict__ ws_ends,
    float* __restrict__ out_mask)
{
    __shared__ int s_cum[SEQ];

    const int tid = threadIdx.x;
    const int b = blockIdx.x;
    const int maxlen = max_len_p[0];

    s_cum[tid] = durations[b * SEQ + tid];
    __syncthreads();
    #pragma unroll
    for (int off = 1; off < SEQ; off <<= 1) {
        int v = (tid >= off) ? s_cum[tid - off] : 0;
        __syncthreads();
        s_cum[tid] += v;
        __syncthreads();
    }

    ws_ends[b * SEQ + tid] = min(s_cum[tid], maxlen);
    const int total = min(s_cum[SEQ - 1], maxlen);

    #pragma unroll
    for (int t = tid; t < MAXL; t += SEQ)
        out_mask[b * MAXL + t] = (t >= total) ? 1.0f : 0.0f;
}

// Kernel 2: scatter expand. Frame blocks: load x row once (coalesced),
// stream (e-st) contiguous 1536B row-stores — no dependent loads in the loop.
// Zero blocks: fill rows >= total with zeros. Intervals are disjoint and tile
// [0,total), matching searchsorted(ends, t, 'right') incl. zero-length frames.
__global__ __launch_bounds__(128) void lr_scatter_kernel(
    const v4f* __restrict__ x,
    const int* __restrict__ ws_ends,
    v4f* __restrict__ out)
{
    const int tid = threadIdx.x;
    const int bid = blockIdx.x;

    if (bid < BATCH * SEQ) {
        // one source frame per block
        const int b = bid >> 9;                  // SEQ = 512
        const int j = bid & (SEQ - 1);
        const int e  = ws_ends[bid];             // wave-uniform -> s_load
        const int st = j ? ws_ends[bid - 1] : 0;
        if (tid >= CH4 || e <= st) return;       // lanes 96..127 idle
        v4f v = x[(size_t)bid * CH4 + tid];      // single coalesced row read
        v4f* ob = out + ((size_t)(b << 12) + st) * CH4 + tid;
        for (int t = st; t < e; ++t) {           // <=16 independent row stores
            *ob = v;
            ob += CH4;
        }
    } else {
        // zero-fill rows t in [total, MAXL)
        const int z = bid - BATCH * SEQ;
        const int b = z >> 6;                    // ZBLK = 64
        const int i = z & (ZBLK - 1);
        const int total = ws_ends[b * SEQ + SEQ - 1];
        if (tid >= CH4) return;
        const v4f zero = (v4f){0.f, 0.f, 0.f, 0.f};
        for (int t = total + i; t < MAXL; t += ZBLK)
            out[((size_t)(b << 12) + t) * CH4 + tid] = zero;
    }
}

extern "C" void kernel_launch(void* const* d_in, const int* in_sizes, int n_in,
                              void* d_out, int out_size, void* d_ws, size_t ws_size,
                              hipStream_t stream) {
    const v4f* x = (const v4f*)d_in[0];
    const int* durations = (const int*)d_in[1];
    const int* max_len_p = (const int*)d_in[2];
    float* out = (float*)d_out;
    float* out_mask = out + (size_t)BATCH * MAXL * CH;
    int* ws_ends = (int*)d_ws;   // BATCH*SEQ ints = 64 KB

    lr_scan_kernel<<<BATCH, SEQ, 0, stream>>>(durations, max_len_p, ws_ends, out_mask);
    lr_scatter_kernel<<<BATCH * SEQ + BATCH * ZBLK, 128, 0, stream>>>(
        x, ws_ends, (v4f*)out);
}

// Round 6
// 216.242 us; speedup vs baseline: 1.1016x; 1.0120x over previous
//
#include <hip/hip_runtime.h>

#define BATCH 32
#define SEQ 512
#define CH4 96            // float4 per channel row (384 ch)
#define MAXL 4096
#define ZBLK 64           // zero-fill blocks per batch
#define FBLKS (BATCH * SEQ)
#define THREADS 128

typedef float v4f __attribute__((ext_vector_type(4)));
typedef int   v4i __attribute__((ext_vector_type(4)));

// Single fused dispatch. Every block recomputes its batch's duration cumsum
// with a barrier-free wave scan (wave 0 only, 6 shfl steps), then:
//  - frame blocks (bid < 32*512): frame j's x-row (1536 B, register-resident)
//    streamed to its disjoint output interval [ends[j-1], ends[j]) as <=15
//    contiguous coalesced stores; mask zeros for those rows.
//  - zero blocks: rows [total, 4096) zero-filled + mask ones.
// Intervals tile [0,total) exactly == searchsorted(ends, t, 'right') semantics.
__global__ __launch_bounds__(THREADS) void lr_fused(
    const v4f* __restrict__ x,
    const v4i* __restrict__ dur4,
    const int* __restrict__ max_len_p,
    v4f* __restrict__ out,
    float* __restrict__ out_mask)
{
    __shared__ int s_end[SEQ];

    const int tid = threadIdx.x;
    const int bid = blockIdx.x;
    const bool is_frame = (bid < FBLKS);
    const int b = is_frame ? (bid >> 9) : ((bid - FBLKS) >> 6);

    // --- wave-0 scan: 512 durations -> clipped inclusive ends in LDS ---
    if (tid < 64) {
        const v4i* dp = dur4 + b * (SEQ / 4) + tid * 2;   // 8 ints/lane, blocked
        v4i d0 = dp[0], d1 = dp[1];                        // L2-hot broadcast
        int lane_sum = d0.x + d0.y + d0.z + d0.w + d1.x + d1.y + d1.z + d1.w;
        int incl = lane_sum;
        #pragma unroll
        for (int off = 1; off < 64; off <<= 1) {
            int v = __shfl_up(incl, off, 64);
            if (tid >= off) incl += v;
        }
        int cum = incl - lane_sum;                         // exclusive prefix
        const int maxlen = max_len_p[0];
        const int base = tid * 8;
        cum += d0.x; s_end[base + 0] = min(cum, maxlen);
        cum += d0.y; s_end[base + 1] = min(cum, maxlen);
        cum += d0.z; s_end[base + 2] = min(cum, maxlen);
        cum += d0.w; s_end[base + 3] = min(cum, maxlen);
        cum += d1.x; s_end[base + 4] = min(cum, maxlen);
        cum += d1.y; s_end[base + 5] = min(cum, maxlen);
        cum += d1.z; s_end[base + 6] = min(cum, maxlen);
        cum += d1.w; s_end[base + 7] = min(cum, maxlen);
    }
    __syncthreads();

    if (is_frame) {
        const int j  = bid & (SEQ - 1);
        const int e  = s_end[j];
        const int st = j ? s_end[j - 1] : 0;
        const int n  = e - st;                   // 0..15
        if (n <= 0) return;
        if (tid < n)                             // mask zeros for covered rows
            out_mask[(b << 12) + st + tid] = 0.0f;
        if (tid < CH4) {
            v4f v = x[(size_t)bid * CH4 + tid];  // one coalesced row read
            v4f* ob = out + ((size_t)(b << 12) + st) * CH4 + tid;
            for (int k = 0; k < n; ++k) {        // independent contiguous stores
                *ob = v;
                ob += CH4;
            }
        }
    } else {
        const int i = (bid - FBLKS) & (ZBLK - 1);
        const int total = s_end[SEQ - 1];
        const v4f zero = (v4f){0.f, 0.f, 0.f, 0.f};
        for (int t = total + i; t < MAXL; t += ZBLK) {
            if (tid < CH4)
                out[((size_t)(b << 12) + t) * CH4 + tid] = zero;
            else if (tid == CH4)
                out_mask[(b << 12) + t] = 1.0f;
        }
    }
}

extern "C" void kernel_launch(void* const* d_in, const int* in_sizes, int n_in,
                              void* d_out, int out_size, void* d_ws, size_t ws_size,
                              hipStream_t stream) {
    const v4f* x = (const v4f*)d_in[0];
    const v4i* dur4 = (const v4i*)d_in[1];
    const int* max_len_p = (const int*)d_in[2];
    float* out = (float*)d_out;
    float* out_mask = out + (size_t)BATCH * MAXL * CH4 * 4;

    lr_fused<<<FBLKS + BATCH * ZBLK, THREADS, 0, stream>>>(
        x, dur4, max_len_p, (v4f*)out, out_mask);
}

// Round 7
// 215.112 us; speedup vs baseline: 1.1074x; 1.0053x over previous
//
#include <hip/hip_runtime.h>

#define BATCH 32
#define SEQ 512
#define CH4 96            // float4 per channel row (384 ch)
#define MAXL 4096
#define FPB 8             // frames per block
#define CPB 64            // chunks (blocks) per batch = SEQ/FPB
#define THREADS 128

typedef float v4f __attribute__((ext_vector_type(4)));
typedef int   v4i __attribute__((ext_vector_type(4)));

// One dispatch, 2048 blocks (all co-resident: 8/CU x 2 waves).
// Block (b, chunk) owns frames j0=chunk*8 .. j0+7:
//   1. lanes<96 issue 8 independent x-row loads FIRST (overlap the scan)
//   2. wave 0: barrier-free shfl scan of the batch's 512 durations -> s_end
//   3. one __syncthreads
//   4. pure store phase: ~60 contiguous 1536B row-stores per block, no loads
//   5. same block zero-fills tail rows [total+chunk::64) and writes mask
// Intervals [ends[j-1],ends[j]) tile [0,total) == searchsorted 'right'.
__global__ __launch_bounds__(THREADS) void lr_fused(
    const v4f* __restrict__ x,
    const v4i* __restrict__ dur4,
    const int* __restrict__ max_len_p,
    v4f* __restrict__ out,
    float* __restrict__ out_mask)
{
    __shared__ int s_end[SEQ];

    const int tid   = threadIdx.x;
    const int bid   = blockIdx.x;
    const int b     = bid >> 6;            // CPB = 64
    const int chunk = bid & (CPB - 1);
    const int j0    = chunk * FPB;

    // --- 1. front-loaded x-row reads (independent of the scan) ---
    v4f vx[FPB];
    if (tid < CH4) {
        const v4f* xp = x + ((size_t)(b * SEQ + j0)) * CH4 + tid;
        #pragma unroll
        for (int fr = 0; fr < FPB; ++fr) vx[fr] = xp[fr * CH4];
    }

    // --- 2. wave-0 scan: 512 durations -> clipped inclusive ends (R6-proven) ---
    if (tid < 64) {
        const v4i* dp = dur4 + b * (SEQ / 4) + tid * 2;   // 8 ints/lane
        v4i d0 = dp[0], d1 = dp[1];
        int lane_sum = d0.x + d0.y + d0.z + d0.w + d1.x + d1.y + d1.z + d1.w;
        int incl = lane_sum;
        #pragma unroll
        for (int off = 1; off < 64; off <<= 1) {
            int v = __shfl_up(incl, off, 64);
            if (tid >= off) incl += v;
        }
        int cum = incl - lane_sum;                        // exclusive prefix
        const int maxlen = max_len_p[0];
        const int base = tid * 8;
        cum += d0.x; s_end[base + 0] = min(cum, maxlen);
        cum += d0.y; s_end[base + 1] = min(cum, maxlen);
        cum += d0.z; s_end[base + 2] = min(cum, maxlen);
        cum += d0.w; s_end[base + 3] = min(cum, maxlen);
        cum += d1.x; s_end[base + 4] = min(cum, maxlen);
        cum += d1.y; s_end[base + 5] = min(cum, maxlen);
        cum += d1.z; s_end[base + 6] = min(cum, maxlen);
        cum += d1.w; s_end[base + 7] = min(cum, maxlen);
    }
    __syncthreads();

    const int st0   = j0 ? s_end[j0 - 1] : 0;
    const int e7    = s_end[j0 + FPB - 1];
    const int total = s_end[SEQ - 1];

    // --- mask zeros for this chunk's covered rows (<= 8*15 = 120 < 128) ---
    if (tid < e7 - st0) out_mask[(b << 12) + st0 + tid] = 0.0f;

    // --- 4. pure store streaming: no loads in the loop ---
    if (tid < CH4) {
        v4f* const ob_base = out + ((size_t)(b << 12)) * CH4 + tid;
        #pragma unroll
        for (int fr = 0; fr < FPB; ++fr) {
            const int jj = j0 + fr;
            const int e  = s_end[jj];
            const int st = jj ? s_end[jj - 1] : 0;
            v4f v = vx[fr];
            v4f* ob = ob_base + (size_t)st * CH4;
            for (int t = st; t < e; ++t) {    // independent contiguous stores
                *ob = v;
                ob += CH4;
            }
        }
    }

    // --- 5. tail zero rows [total, MAXL), strided across the 64 chunks ---
    const v4f zero = (v4f){0.f, 0.f, 0.f, 0.f};
    for (int t = total + chunk; t < MAXL; t += CPB) {
        if (tid < CH4)
            out[((size_t)(b << 12) + t) * CH4 + tid] = zero;
        else if (tid == CH4)
            out_mask[(b << 12) + t] = 1.0f;
    }
}

extern "C" void kernel_launch(void* const* d_in, const int* in_sizes, int n_in,
                              void* d_out, int out_size, void* d_ws, size_t ws_size,
                              hipStream_t stream) {
    const v4f* x = (const v4f*)d_in[0];
    const v4i* dur4 = (const v4i*)d_in[1];
    const int* max_len_p = (const int*)d_in[2];
    float* out = (float*)d_out;
    float* out_mask = out + (size_t)BATCH * MAXL * CH4 * 4;

    lr_fused<<<BATCH * CPB, THREADS, 0, stream>>>(
        x, dur4, max_len_p, (v4f*)out, out_mask);
}